// Round 15
// baseline (74.500 us; speedup 1.0000x reference)
//
#include <hip/hip_runtime.h>
#include <hip/hip_bf16.h>

// TT embedding — R15 PROBE ROUND (R14 kernel + reps=3, v laundered per rep).
// R11/R13/R14 all plateau at 26.3-26.6us with counters blind (fills dominate
// top-5). This probe makes the dispatch ~80us to read VGPR_Count / Occupancy /
// VALUBusy / LDS conflicts for the R14 structure and split the decision tree:
//   occupancy rose & VALU low  -> latency chains: pipeline across tokens
//   VGPR>64 or scratch fetch   -> the (256,8) cap failed: restructure regs
//   VALUBusy >= 50%            -> issue-bound: cut instruction count
//
// out[v,d] = sum_{r1..r4} c0[0,i0,r1] c1[r1,i1,r2] c2[r2,i2,r3] c3[r3,i3,r4] c4[r4,i4,0]
//   i0=v>>11, i1=(v>>6)&31, i2=(v>>1)&31, i3=(v&1)*16+(d>>6), i4=d&63

#define RSTRIDE 20          // words per w4 row
#define GSTRIDE 328         // 16*20+8; mod 32 = 8 -> slabs bank-staggered

__global__ __launch_bounds__(256, 8) void tt_embed_kernel(
    const float* __restrict__ c0,   // 32*16
    const float* __restrict__ c1,   // 16*32*16
    const float* __restrict__ c2,   // 16*32*16
    const float* __restrict__ c3,   // 16*32*16
    const float* __restrict__ c4,   // 16*64
    const int*   __restrict__ idx,  // n_tokens
    float*       __restrict__ out,  // n_tokens x 1024
    int n_tokens, int reps)
{
    const int t   = threadIdx.x;
    const int tl  = t >> 5;          // token slot in block (0..7)
    const int l32 = t & 31;          // lane within token (stages 1-3)
    const int r   = t & 15;          // rank lane
    const int l   = t & 63;          // lane in wave = output column (stage 4)
    const int wid = t >> 6;          // wave in block (0..3)
    const int token = blockIdx.x * 8 + tl;
    const int v0 = (token < n_tokens) ? idx[token] : 0;

    __shared__ float w4s[8 * GSTRIDE];   // 10.5 KB

    // ---- c4: ONE column per lane -> 16 VGPRs. Coalesced 256B loads.
    float c4v[16];
    #pragma unroll
    for (int r4 = 0; r4 < 16; ++r4)
        c4v[r4] = c4[(r4 << 6) + l];

    for (int rep = 0; rep < reps; ++rep) {
        int v = v0;
        asm volatile("" : "+v"(v));   // opaque per rep: defeats LICM/CSE

        // ---- Stage 1: w2[r] = sum_r1 c0[i0,r1] * c1[r1,i1,r]
        float w2r = 0.f;
        {
            const int i0 = (v >> 11) & 31;
            const int i1 = (v >> 6) & 31;
            #pragma unroll
            for (int r1 = 0; r1 < 16; ++r1)
                w2r = fmaf(c0[i0 * 16 + r1], c1[(r1 * 32 + i1) * 16 + r], w2r);
        }

        // ---- Stage 2: w3[r] = sum_r2 w2[r2] * c2[r2,i2,r]
        float w3r = 0.f;
        {
            const int i2 = (v >> 1) & 31;
            #pragma unroll
            for (int r2 = 0; r2 < 16; ++r2)
                w3r = fmaf(__shfl(w2r, r2, 16), c2[(r2 * 32 + i2) * 16 + r], w3r);
        }

        // ---- Stage 3: two contiguous 512B halves per r3; same-wave scatter
        {
            const int vlow16 = (v & 1) << 4;
            float4 a0 = {0,0,0,0}, a1 = {0,0,0,0};
            #pragma unroll
            for (int r3 = 0; r3 < 16; ++r3) {
                const float wv = __shfl(w3r, r3, 16);
                const float* base = c3 + ((r3 * 32 + vlow16) << 4);
                const float4 b0 = *(const float4*)(base + (l32 << 2));
                const float4 b1 = *(const float4*)(base + 128 + (l32 << 2));
                a0.x = fmaf(wv, b0.x, a0.x); a0.y = fmaf(wv, b0.y, a0.y);
                a0.z = fmaf(wv, b0.z, a0.z); a0.w = fmaf(wv, b0.w, a0.w);
                a1.x = fmaf(wv, b1.x, a1.x); a1.y = fmaf(wv, b1.y, a1.y);
                a1.z = fmaf(wv, b1.z, a1.z); a1.w = fmaf(wv, b1.w, a1.w);
            }
            float* sb = &w4s[tl * GSTRIDE + ((l32 & 3) << 2)];
            *(float4*)(sb + ((l32 >> 2)    ) * RSTRIDE) = a0;
            *(float4*)(sb + (8 + (l32 >> 2)) * RSTRIDE) = a1;
        }

        // ---- Stage 4: wave's 2 tokens sequentially; wave-uniform row
        // broadcasts; 256B/instr contiguous dword stores.
        #pragma unroll
        for (int s = 0; s < 2; ++s) {
            const int slot = 2 * wid + s;
            const int tok  = blockIdx.x * 8 + slot;
            const float* slab = &w4s[slot * GSTRIDE];
            float* outp = out + (size_t)tok * 1024 + l;

            #pragma unroll
            for (int k = 0; k < 16; ++k) {
                const float4* wp = (const float4*)(slab + k * RSTRIDE);
                const float4 wa = wp[0], wb = wp[1], wc = wp[2], wd = wp[3];

                float acc = 0.f;
                acc = fmaf(wa.x, c4v[ 0], acc);
                acc = fmaf(wa.y, c4v[ 1], acc);
                acc = fmaf(wa.z, c4v[ 2], acc);
                acc = fmaf(wa.w, c4v[ 3], acc);
                acc = fmaf(wb.x, c4v[ 4], acc);
                acc = fmaf(wb.y, c4v[ 5], acc);
                acc = fmaf(wb.z, c4v[ 6], acc);
                acc = fmaf(wb.w, c4v[ 7], acc);
                acc = fmaf(wc.x, c4v[ 8], acc);
                acc = fmaf(wc.y, c4v[ 9], acc);
                acc = fmaf(wc.z, c4v[10], acc);
                acc = fmaf(wc.w, c4v[11], acc);
                acc = fmaf(wd.x, c4v[12], acc);
                acc = fmaf(wd.y, c4v[13], acc);
                acc = fmaf(wd.z, c4v[14], acc);
                acc = fmaf(wd.w, c4v[15], acc);

                if (tok < n_tokens)
                    __builtin_nontemporal_store(acc, outp + (k << 6));
            }
        }
    }
}

extern "C" void kernel_launch(void* const* d_in, const int* in_sizes, int n_in,
                              void* d_out, int out_size, void* d_ws, size_t ws_size,
                              hipStream_t stream) {
    const float* c0  = (const float*)d_in[0];
    const float* c1  = (const float*)d_in[1];
    const float* c2  = (const float*)d_in[2];
    const float* c3  = (const float*)d_in[3];
    const float* c4  = (const float*)d_in[4];
    const int*   idx = (const int*)d_in[5];
    float* out = (float*)d_out;

    const int n_tokens = in_sizes[5];              // 8 * 2048 = 16384
    const int grid = (n_tokens + 7) / 8;           // 2048
    tt_embed_kernel<<<grid, 256, 0, stream>>>(c0, c1, c2, c3, c4, idx, out,
                                              n_tokens, /*reps=*/3);
}

// Round 16
// 25.588 us; speedup vs baseline: 2.9115x; 2.9115x over previous
//
#include <hip/hip_runtime.h>
#include <hip/hip_bf16.h>

// TT embedding: vocab 65536, dim 1024, rank 16.
// out[v,d] = sum_{r1..r4} c0[0,i0,r1] c1[r1,i1,r2] c2[r2,i2,r3] c3[r3,i3,r4] c4[r4,i4,0]
//   i0=v>>11, i1=(v>>6)&31, i2=(v>>1)&31, i3=(v&1)*16+(d>>6), i4=d&63
//
// R15 probe: VGPR=32, occ 65%, VALU 33%, HBM ~idle (output lands in L3!) yet
// 26.7us/rep -> the saturated resource is the per-CU LDS pipe: ~164 LDS
// instrs/wave (32 bpermute from __shfl + 128 16B-broadcast ds_read_b128 +
// writes) x 32 waves/CU x ~12cyc ~= 63k cyc ~= 26us. R16 cuts LDS ops ~4x:
//  - NO shfl anywhere: w2/w3 go through LDS once (1 write + 4 b128 broadcast
//    reads each) into per-lane register copies w2v/w3v
//  - stage 4: 4 rows per read instr (sub-group<->row, quarter broadcast,
//    banks {0-3,20-23,8-11,28-31} disjoint); 16-reg row; 1KB contiguous
//    float4 stores (8 store instrs/wave instead of 32)
//  - per-element FMA association identical to R11/R14 -> absmax 0.0
// Per token: ~22 LDS instrs vs R14's ~80. 2048 blocks x 8 tokens.

typedef float f32x4 __attribute__((ext_vector_type(4)));

#define RSTRIDE 20          // words per w4 row
#define GSTRIDE 328         // 16*20+8; mod 32 = 8 -> slabs bank-staggered

__global__ __launch_bounds__(256) void tt_embed_kernel(
    const float* __restrict__ c0,   // 32*16
    const float* __restrict__ c1,   // 16*32*16
    const float* __restrict__ c2,   // 16*32*16
    const float* __restrict__ c3,   // 16*32*16
    const float* __restrict__ c4,   // 16*64
    const int*   __restrict__ idx,  // n_tokens
    float*       __restrict__ out,  // n_tokens x 1024
    int n_tokens)
{
    const int t   = threadIdx.x;
    const int tl  = t >> 5;          // token slot in block (0..7)
    const int l32 = t & 31;          // lane within token (stages 1-3)
    const int r   = t & 15;          // rank lane (stages 1-2)
    const int l   = t & 63;          // lane in wave (stage 4)
    const int wid = t >> 6;          // wave in block (0..3)
    const int token = blockIdx.x * 8 + tl;
    const int v = (token < n_tokens) ? idx[token] : 0;

    __shared__ float w4s[8 * GSTRIDE];   // 10.5 KB
    __shared__ float w2b[8][20];
    __shared__ float w3b[8][20];

    // ---- c4 slice: lane l covers cols (l&15)*4..+3 for all 16 r4 -> 64 VGPRs
    float4 c4v[16];
    #pragma unroll
    for (int r4 = 0; r4 < 16; ++r4)
        c4v[r4] = *(const float4*)(c4 + (r4 << 6) + ((l & 15) << 2));

    // ---- Stage 1: w2[r] = sum_r1 c0[i0,r1] * c1[r1,i1,r] (both halves dup)
    {
        const int i0 = (v >> 11) & 31;
        const int i1 = (v >> 6) & 31;
        float w2r = 0.f;
        #pragma unroll
        for (int r1 = 0; r1 < 16; ++r1)
            w2r = fmaf(c0[i0 * 16 + r1], c1[(r1 * 32 + i1) * 16 + r], w2r);
        w2b[tl][r] = w2r;            // dup write from both halves: same data
    }

    // broadcast-read all 16 w2 into registers (4 b128, same-wave RAW)
    float4 w2v[4];
    #pragma unroll
    for (int q = 0; q < 4; ++q)
        w2v[q] = *(const float4*)&w2b[tl][q << 2];

    // ---- Stage 2: w3[r] = sum_r2 w2[r2] * c2[r2,i2,r] (register weights)
    {
        const int i2 = (v >> 1) & 31;
        float w3r = 0.f;
        #pragma unroll
        for (int q = 0; q < 4; ++q) {
            w3r = fmaf(w2v[q].x, c2[((q * 4 + 0) * 32 + i2) * 16 + r], w3r);
            w3r = fmaf(w2v[q].y, c2[((q * 4 + 1) * 32 + i2) * 16 + r], w3r);
            w3r = fmaf(w2v[q].z, c2[((q * 4 + 2) * 32 + i2) * 16 + r], w3r);
            w3r = fmaf(w2v[q].w, c2[((q * 4 + 3) * 32 + i2) * 16 + r], w3r);
        }
        w3b[tl][r] = w3r;
    }

    float4 w3v[4];
    #pragma unroll
    for (int q = 0; q < 4; ++q)
        w3v[q] = *(const float4*)&w3b[tl][q << 2];

    // ---- Stage 3: token's 32 lanes read its 1KB c3 block as two contiguous
    // 512B halves per r3; weights from registers (no shfl). Lane l32 owns
    // quarter (l32&3) of rows (l32>>2) and 8+(l32>>2). Same r3 order.
    {
        const int vlow16 = (v & 1) << 4;
        float4 a0 = {0,0,0,0}, a1 = {0,0,0,0};
        const float wv_arr0[16] = {w3v[0].x, w3v[0].y, w3v[0].z, w3v[0].w,
                                   w3v[1].x, w3v[1].y, w3v[1].z, w3v[1].w,
                                   w3v[2].x, w3v[2].y, w3v[2].z, w3v[2].w,
                                   w3v[3].x, w3v[3].y, w3v[3].z, w3v[3].w};
        #pragma unroll
        for (int r3 = 0; r3 < 16; ++r3) {
            const float wv = wv_arr0[r3];
            const float* base = c3 + ((r3 * 32 + vlow16) << 4);
            const float4 b0 = *(const float4*)(base + (l32 << 2));        // rows 0..7
            const float4 b1 = *(const float4*)(base + 128 + (l32 << 2));  // rows 8..15
            a0.x = fmaf(wv, b0.x, a0.x); a0.y = fmaf(wv, b0.y, a0.y);
            a0.z = fmaf(wv, b0.z, a0.z); a0.w = fmaf(wv, b0.w, a0.w);
            a1.x = fmaf(wv, b1.x, a1.x); a1.y = fmaf(wv, b1.y, a1.y);
            a1.z = fmaf(wv, b1.z, a1.z); a1.w = fmaf(wv, b1.w, a1.w);
        }
        // same-wave LDS scatter
        float* sb = &w4s[tl * GSTRIDE + ((l32 & 3) << 2)];
        *(float4*)(sb + ((l32 >> 2)    ) * RSTRIDE) = a0;
        *(float4*)(sb + (8 + (l32 >> 2)) * RSTRIDE) = a1;
    }

    // ---- Stage 4: wave handles its 2 tokens sequentially with all 64 lanes.
    // Lane l: row = 4j + (l>>4), cols (l&15)*4..+3. Reads: 4 b128 per j
    // (quarter broadcast within 16-lane sub-group; rows' banks disjoint).
    // Stores: one float4 per j per token -> 1KB contiguous per instr.
    #pragma unroll
    for (int s = 0; s < 2; ++s) {
        const int slot = 2 * wid + s;
        const int tok  = blockIdx.x * 8 + slot;
        const float* slab = &w4s[slot * GSTRIDE];
        const int sub = l >> 4;              // 0..3
        const int colb = (l & 15) << 2;      // col base

        #pragma unroll
        for (int j = 0; j < 4; ++j) {
            const int row = (j << 2) + sub;
            const float* rp = slab + row * RSTRIDE;
            const float4 wa = *(const float4*)(rp);
            const float4 wb = *(const float4*)(rp + 4);
            const float4 wc = *(const float4*)(rp + 8);
            const float4 wd = *(const float4*)(rp + 12);

            float4 acc = {0,0,0,0};
            #define FMA4(WV, k)                          \
                acc.x = fmaf(WV, c4v[k].x, acc.x);       \
                acc.y = fmaf(WV, c4v[k].y, acc.y);       \
                acc.z = fmaf(WV, c4v[k].z, acc.z);       \
                acc.w = fmaf(WV, c4v[k].w, acc.w);
            FMA4(wa.x,  0) FMA4(wa.y,  1) FMA4(wa.z,  2) FMA4(wa.w,  3)
            FMA4(wb.x,  4) FMA4(wb.y,  5) FMA4(wb.z,  6) FMA4(wb.w,  7)
            FMA4(wc.x,  8) FMA4(wc.y,  9) FMA4(wc.z, 10) FMA4(wc.w, 11)
            FMA4(wd.x, 12) FMA4(wd.y, 13) FMA4(wd.z, 14) FMA4(wd.w, 15)
            #undef FMA4

            if (tok < n_tokens)
                __builtin_nontemporal_store(*(const f32x4*)&acc,
                    (f32x4*)(out + (size_t)tok * 1024 + (row << 6) + colb));
        }
    }
}

extern "C" void kernel_launch(void* const* d_in, const int* in_sizes, int n_in,
                              void* d_out, int out_size, void* d_ws, size_t ws_size,
                              hipStream_t stream) {
    const float* c0  = (const float*)d_in[0];
    const float* c1  = (const float*)d_in[1];
    const float* c2  = (const float*)d_in[2];
    const float* c3  = (const float*)d_in[3];
    const float* c4  = (const float*)d_in[4];
    const int*   idx = (const int*)d_in[5];
    float* out = (float*)d_out;

    const int n_tokens = in_sizes[5];              // 8 * 2048 = 16384
    const int grid = (n_tokens + 7) / 8;           // 2048
    tt_embed_kernel<<<grid, 256, 0, stream>>>(c0, c1, c2, c3, c4, idx, out, n_tokens);
}

// Round 17
// 24.440 us; speedup vs baseline: 3.0483x; 1.0470x over previous
//
#include <hip/hip_runtime.h>
#include <hip/hip_bf16.h>

// TT embedding: vocab 65536, dim 1024, rank 16.
// out[v,d] = sum_{r1..r4} c0[0,i0,r1] c1[r1,i1,r2] c2[r2,i2,r3] c3[r3,i3,r4] c4[r4,i4,0]
//   i0=v>>11, i1=(v>>6)&31, i2=(v>>1)&31, i3=(v&1)*16+(d>>6), i4=d&63
//
// R16 lesson: all pipes at 30-40% yet time = SUM of phases: barrier-free
// identical-code waves CONVOY (all in the same phase at once), so vmem/VALU/
// LDS time-share instead of overlapping. R17: software pipeline WITHIN each
// wave: 8 tokens/wave as 4 pairs; S123(pair i+1) interleaved chunk-by-chunk
// with stage4(pair i) through double-buffered wave-private LDS slabs.
// Peeled prologue/epilogue -> hot loop is one branch-free basic block.
// Zero barriers. All FMA orders bit-identical to R16 (absmax 0.0).

typedef float f32x4 __attribute__((ext_vector_type(4)));

#define RSTRIDE 20
#define BUFSTRIDE (2 * 16 * RSTRIDE)          // one buf = 2 tokens x 16 rows
#define WSLAB (2 * BUFSTRIDE + 8)             // per-wave slab (+8: bank stagger)

#define FMA4(WV, K)                              \
    acc.x = fmaf(WV, c4v[K].x, acc.x);           \
    acc.y = fmaf(WV, c4v[K].y, acc.y);           \
    acc.z = fmaf(WV, c4v[K].z, acc.z);           \
    acc.w = fmaf(WV, c4v[K].w, acc.w);

// stage-4 chunk: one row-quad of token (PB+S) from buf BUF
#define PC(BUF, S, J, PB) {                                                   \
    const int tok_ = (PB) + (S);                                              \
    const float* rp = myslab + (BUF) * BUFSTRIDE + (S) * (16 * RSTRIDE)       \
                      + (4 * (J) + sub) * RSTRIDE;                            \
    const float4 qa = *(const float4*)(rp);                                   \
    const float4 qb = *(const float4*)(rp + 4);                               \
    const float4 qc = *(const float4*)(rp + 8);                               \
    const float4 qd = *(const float4*)(rp + 12);                              \
    float4 acc = {0, 0, 0, 0};                                                \
    FMA4(qa.x,  0) FMA4(qa.y,  1) FMA4(qa.z,  2) FMA4(qa.w,  3)               \
    FMA4(qb.x,  4) FMA4(qb.y,  5) FMA4(qb.z,  6) FMA4(qb.w,  7)               \
    FMA4(qc.x,  8) FMA4(qc.y,  9) FMA4(qc.z, 10) FMA4(qc.w, 11)               \
    FMA4(qd.x, 12) FMA4(qd.y, 13) FMA4(qd.z, 14) FMA4(qd.w, 15)               \
    if (tok_ < n_tokens)                                                      \
        __builtin_nontemporal_store(*(const f32x4*)&acc,                      \
            (f32x4*)(out + (size_t)tok_ * 1024 + ((4 * (J) + sub) << 6) + colb)); }

// stage 1: w2 + LDS round-trip into w2v* registers
#define N_S1(VV, BUF) {                                                       \
    const int i0 = ((VV) >> 11) & 31, i1 = ((VV) >> 6) & 31;                  \
    const float* c0b = c0 + i0 * 16;                                          \
    const float* c1b = c1 + i1 * 16 + r;                                      \
    w2r = 0.f;                                                                \
    w2r = fmaf(c0b[ 0], c1b[ 0 * 512], w2r);                                  \
    w2r = fmaf(c0b[ 1], c1b[ 1 * 512], w2r);                                  \
    w2r = fmaf(c0b[ 2], c1b[ 2 * 512], w2r);                                  \
    w2r = fmaf(c0b[ 3], c1b[ 3 * 512], w2r);                                  \
    w2r = fmaf(c0b[ 4], c1b[ 4 * 512], w2r);                                  \
    w2r = fmaf(c0b[ 5], c1b[ 5 * 512], w2r);                                  \
    w2r = fmaf(c0b[ 6], c1b[ 6 * 512], w2r);                                  \
    w2r = fmaf(c0b[ 7], c1b[ 7 * 512], w2r);                                  \
    w2r = fmaf(c0b[ 8], c1b[ 8 * 512], w2r);                                  \
    w2r = fmaf(c0b[ 9], c1b[ 9 * 512], w2r);                                  \
    w2r = fmaf(c0b[10], c1b[10 * 512], w2r);                                  \
    w2r = fmaf(c0b[11], c1b[11 * 512], w2r);                                  \
    w2r = fmaf(c0b[12], c1b[12 * 512], w2r);                                  \
    w2r = fmaf(c0b[13], c1b[13 * 512], w2r);                                  \
    w2r = fmaf(c0b[14], c1b[14 * 512], w2r);                                  \
    w2r = fmaf(c0b[15], c1b[15 * 512], w2r);                                  \
    w23[wid][BUF][0][tl2][r] = w2r;                                           \
    w2v0 = *(const float4*)&w23[wid][BUF][0][tl2][0];                         \
    w2v1 = *(const float4*)&w23[wid][BUF][0][tl2][4];                         \
    w2v2 = *(const float4*)&w23[wid][BUF][0][tl2][8];                         \
    w2v3 = *(const float4*)&w23[wid][BUF][0][tl2][12];                        \
    sa0 = (float4){0, 0, 0, 0};                                               \
    sa1 = (float4){0, 0, 0, 0}; }

// stage 2: w3 + LDS round-trip into w3v* registers (r2 order 0..15)
#define N_S2(VV, BUF) {                                                       \
    const int i2 = ((VV) >> 1) & 31;                                          \
    const float* c2b = c2 + i2 * 16 + r;                                      \
    w3r = 0.f;                                                                \
    w3r = fmaf(w2v0.x, c2b[ 0 * 512], w3r);                                   \
    w3r = fmaf(w2v0.y, c2b[ 1 * 512], w3r);                                   \
    w3r = fmaf(w2v0.z, c2b[ 2 * 512], w3r);                                   \
    w3r = fmaf(w2v0.w, c2b[ 3 * 512], w3r);                                   \
    w3r = fmaf(w2v1.x, c2b[ 4 * 512], w3r);                                   \
    w3r = fmaf(w2v1.y, c2b[ 5 * 512], w3r);                                   \
    w3r = fmaf(w2v1.z, c2b[ 6 * 512], w3r);                                   \
    w3r = fmaf(w2v1.w, c2b[ 7 * 512], w3r);                                   \
    w3r = fmaf(w2v2.x, c2b[ 8 * 512], w3r);                                   \
    w3r = fmaf(w2v2.y, c2b[ 9 * 512], w3r);                                   \
    w3r = fmaf(w2v2.z, c2b[10 * 512], w3r);                                   \
    w3r = fmaf(w2v2.w, c2b[11 * 512], w3r);                                   \
    w3r = fmaf(w2v3.x, c2b[12 * 512], w3r);                                   \
    w3r = fmaf(w2v3.y, c2b[13 * 512], w3r);                                   \
    w3r = fmaf(w2v3.z, c2b[14 * 512], w3r);                                   \
    w3r = fmaf(w2v3.w, c2b[15 * 512], w3r);                                   \
    w23[wid][BUF][1][tl2][r] = w3r;                                           \
    w3v0 = *(const float4*)&w23[wid][BUF][1][tl2][0];                         \
    w3v1 = *(const float4*)&w23[wid][BUF][1][tl2][4];                         \
    w3v2 = *(const float4*)&w23[wid][BUF][1][tl2][8];                         \
    w3v3 = *(const float4*)&w23[wid][BUF][1][tl2][12];                        \
}

#define S3STEP(W, OFF) {                                                      \
    const float4 b0 = *(const float4*)(c3b + (OFF));                          \
    const float4 b1 = *(const float4*)(c3b + (OFF) + 128);                    \
    sa0.x = fmaf(W, b0.x, sa0.x); sa0.y = fmaf(W, b0.y, sa0.y);               \
    sa0.z = fmaf(W, b0.z, sa0.z); sa0.w = fmaf(W, b0.w, sa0.w);               \
    sa1.x = fmaf(W, b1.x, sa1.x); sa1.y = fmaf(W, b1.y, sa1.y);               \
    sa1.z = fmaf(W, b1.z, sa1.z); sa1.w = fmaf(W, b1.w, sa1.w); }

// stage-3 quarter: r3 = R3B..R3B+3 with weights W0..W3
#define N_S3Q(VV, W0, W1, W2, W3, R3B) {                                      \
    const float* c3b = c3 + (((VV) & 1) << 8) + (l32 << 2);                   \
    S3STEP(W0, ((R3B) + 0) * 512)                                             \
    S3STEP(W1, ((R3B) + 1) * 512)                                             \
    S3STEP(W2, ((R3B) + 2) * 512)                                             \
    S3STEP(W3, ((R3B) + 3) * 512) }

#define N_SCATTER(BUF) {                                                      \
    float* sb = myslab + (BUF) * BUFSTRIDE + tl2 * (16 * RSTRIDE)             \
                + ((l32 & 3) << 2);                                           \
    *(float4*)(sb + (l32 >> 2) * RSTRIDE) = sa0;                              \
    *(float4*)(sb + (8 + (l32 >> 2)) * RSTRIDE) = sa1; }

__global__ __launch_bounds__(256) void tt_embed_kernel(
    const float* __restrict__ c0,   // 32*16
    const float* __restrict__ c1,   // 16*32*16
    const float* __restrict__ c2,   // 16*32*16
    const float* __restrict__ c3,   // 16*32*16
    const float* __restrict__ c4,   // 16*64
    const int*   __restrict__ idx,  // n_tokens
    float*       __restrict__ out,  // n_tokens x 1024
    int n_tokens)
{
    const int t    = threadIdx.x;
    const int wid  = t >> 6;          // wave in block
    const int l    = t & 63;
    const int tl2  = (t >> 5) & 1;    // token half within wave
    const int l32  = t & 31;
    const int r    = t & 15;
    const int sub  = l >> 4;          // stage-4 row sub-index
    const int colb = (l & 15) << 2;   // stage-4 col base

    __shared__ float w4s[4 * WSLAB];            // ~20.6 KB
    __shared__ float w23[4][2][2][2][20];       // ~2.6 KB

    const int wb = (blockIdx.x * 4 + wid) * 8;  // wave's 8-token base
    float* const myslab = &w4s[wid * WSLAB];

    // c4 slice (64 VGPR), reused for all 8 tokens
    float4 c4v[16];
    #pragma unroll
    for (int r4 = 0; r4 < 16; ++r4)
        c4v[r4] = *(const float4*)(c4 + (r4 << 6) + colb);

    float w2r, w3r;
    float4 w2v0, w2v1, w2v2, w2v3;
    float4 w3v0, w3v1, w3v2, w3v3;
    float4 sa0, sa1;

    const int nclamp = n_tokens - 1;

    // ---- prologue: v for pairs 0 and 1; S123(pair 0) -> buf 0
    int a0i = wb + tl2;           if (a0i > nclamp) a0i = nclamp;
    int v0 = idx[a0i];
    int a1i = wb + 2 + tl2;       if (a1i > nclamp) a1i = nclamp;
    int vN = idx[a1i];

    N_S1(v0, 0) N_S2(v0, 0)
    N_S3Q(v0, w3v0.x, w3v0.y, w3v0.z, w3v0.w,  0)
    N_S3Q(v0, w3v1.x, w3v1.y, w3v1.z, w3v1.w,  4)
    N_S3Q(v0, w3v2.x, w3v2.y, w3v2.z, w3v2.w,  8)
    N_S3Q(v0, w3v3.x, w3v3.y, w3v3.z, w3v3.w, 12)
    N_SCATTER(0)

    // ---- main loop: stage4(pair it) interleaved with S123(pair it+1)
    for (int it = 0; it < 3; ++it) {
        const int cur = it & 1, nxt = cur ^ 1;
        const int pb = wb + 2 * it;

        int a2i = wb + 2 * (it + 2) + tl2;    // pair it+2 idx (clamped; unused
        if (a2i > nclamp) a2i = nclamp;       //  garbage on final lap is dead)
        const int vNN = idx[a2i];

        N_S1(vN, nxt)
        PC(cur, 0, 0, pb)
        PC(cur, 0, 1, pb)
        N_S2(vN, nxt)
        PC(cur, 0, 2, pb)
        PC(cur, 0, 3, pb)
        N_S3Q(vN, w3v0.x, w3v0.y, w3v0.z, w3v0.w,  0)
        PC(cur, 1, 0, pb)
        N_S3Q(vN, w3v1.x, w3v1.y, w3v1.z, w3v1.w,  4)
        PC(cur, 1, 1, pb)
        N_S3Q(vN, w3v2.x, w3v2.y, w3v2.z, w3v2.w,  8)
        PC(cur, 1, 2, pb)
        N_S3Q(vN, w3v3.x, w3v3.y, w3v3.z, w3v3.w, 12)
        N_SCATTER(nxt)
        PC(cur, 1, 3, pb)

        vN = vNN;
    }

    // ---- epilogue: stage4(pair 3) from buf 1
    {
        const int pb = wb + 6;
        PC(1, 0, 0, pb) PC(1, 0, 1, pb) PC(1, 0, 2, pb) PC(1, 0, 3, pb)
        PC(1, 1, 0, pb) PC(1, 1, 1, pb) PC(1, 1, 2, pb) PC(1, 1, 3, pb)
    }
}

extern "C" void kernel_launch(void* const* d_in, const int* in_sizes, int n_in,
                              void* d_out, int out_size, void* d_ws, size_t ws_size,
                              hipStream_t stream) {
    const float* c0  = (const float*)d_in[0];
    const float* c1  = (const float*)d_in[1];
    const float* c2  = (const float*)d_in[2];
    const float* c3  = (const float*)d_in[3];
    const float* c4  = (const float*)d_in[4];
    const int*   idx = (const int*)d_in[5];
    float* out = (float*)d_out;

    const int n_tokens = in_sizes[5];              // 8 * 2048 = 16384
    const int grid = (n_tokens + 31) / 32;         // 512 (8 tokens x 4 waves)
    tt_embed_kernel<<<grid, 256, 0, stream>>>(c0, c1, c2, c3, c4, idx, out, n_tokens);
}